// Round 1
// baseline (482.746 us; speedup 1.0000x reference)
//
#include <hip/hip_runtime.h>
#include <math.h>

#define E 1280
#define NHEAD 20
#define HD 64
#define NBLK 7

__device__ __forceinline__ float wave_max64(float v) {
    #pragma unroll
    for (int o = 32; o > 0; o >>= 1) v = fmaxf(v, __shfl_xor(v, o, 64));
    return v;
}
__device__ __forceinline__ float wave_sum64(float v) {
    #pragma unroll
    for (int o = 32; o > 0; o >>= 1) v += __shfl_xor(v, o, 64);
    return v;
}

// C[b][j] = (sum_k A[b][k] * W[j][k] + bias[j]) * scale   for matrix m = j/E
// grid.x = (numMatrices*E)/BN, 256 threads. M=64 rows fixed.
template <int BN>
__global__ __launch_bounds__(256) void proj_gemm(
    const float* __restrict__ A,
    const float* __restrict__ W0, const float* __restrict__ b0,
    const float* __restrict__ W1, const float* __restrict__ b1,
    const float* __restrict__ W2, const float* __restrict__ b2,
    float* __restrict__ C0, float* __restrict__ C1, float* __restrict__ C2,
    float scale0)
{
    constexpr int BK = 32;
    constexpr int RPT = BN / 4;           // rows per thread (64*BN/256)
    __shared__ __align__(16) float As[64][BK + 4];
    __shared__ __align__(16) float Ws[BN][BK + 4];

    const int t = threadIdx.x;
    const int jglob0 = blockIdx.x * BN;
    const int msel = jglob0 / E;          // which matrix (uniform per block)
    const int j0 = jglob0 - msel * E;

    const float* Wsel[3] = {W0, W1, W2};
    const float* bsel[3] = {b0, b1, b2};
    float* Csel[3] = {C0, C1, C2};
    const float* __restrict__ Wp = Wsel[msel];
    const float* __restrict__ bp = bsel[msel];
    float* __restrict__ Cp = Csel[msel];
    const float scl = (msel == 0) ? scale0 : 1.0f;

    const int tx = t % BN;                // column within tile
    const int ty = t / BN;                // row group
    float acc[RPT];
    #pragma unroll
    for (int i = 0; i < RPT; ++i) acc[i] = 0.0f;

    for (int k0 = 0; k0 < E; k0 += BK) {
        // stage A tile: 64 x 32 floats = 512 float4 slots, 2 per thread
        #pragma unroll
        for (int r = 0; r < 2; ++r) {
            int s = t + r * 256;
            int row = s >> 3, c4 = s & 7;
            float4 v = *(const float4*)&A[row * E + k0 + c4 * 4];
            *(float4*)&As[row][c4 * 4] = v;
        }
        // stage W tile: BN x 32 floats = BN*8 float4 slots
        if (t < BN * 8) {
            int row = t >> 3, c4 = t & 7;
            float4 v = *(const float4*)&Wp[(size_t)(j0 + row) * E + k0 + c4 * 4];
            *(float4*)&Ws[row][c4 * 4] = v;
        }
        __syncthreads();

        #pragma unroll
        for (int kk = 0; kk < BK; kk += 4) {
            float4 w4 = *(const float4*)&Ws[tx][kk];
            #pragma unroll
            for (int i = 0; i < RPT; ++i) {
                float4 a4 = *(const float4*)&As[ty * RPT + i][kk];
                acc[i] = fmaf(a4.x, w4.x, acc[i]);
                acc[i] = fmaf(a4.y, w4.y, acc[i]);
                acc[i] = fmaf(a4.z, w4.z, acc[i]);
                acc[i] = fmaf(a4.w, w4.w, acc[i]);
            }
        }
        __syncthreads();
    }

    const float bj = bp[j0 + tx];
    #pragma unroll
    for (int i = 0; i < RPT; ++i) {
        int row = ty * RPT + i;
        Cp[(size_t)row * E + j0 + tx] = (acc[i] + bj) * scl;
    }
}

// One block per (b, h). 256 threads = 4 waves. Flash attention over paged KV.
__global__ __launch_bounds__(256) void attn_kernel(
    const float* __restrict__ qbuf, const float* __restrict__ kbuf,
    const float* __restrict__ vbuf,
    const float* __restrict__ kcache, const float* __restrict__ vcache,
    const int* __restrict__ cache_position, const int* __restrict__ block_tables,
    float* __restrict__ obuf)
{
    const int bh = blockIdx.x;
    const int b = bh / NHEAD;
    const int h = bh % NHEAD;
    const int lane = threadIdx.x & 63;
    const int wv = threadIdx.x >> 6;

    __shared__ __align__(16) float q_lds[64];
    __shared__ float o_lds[4][64];
    __shared__ float ml_lds[4][2];

    const int pos = cache_position[b];
    const int last = pos - 1;             // top cached position
    const int base_e = b * E + h * HD;

    const float qd  = qbuf[base_e + lane];
    const float knd = kbuf[base_e + lane];
    const float vnd = vbuf[base_e + lane];
    if (wv == 0) q_lds[lane] = qd;
    __syncthreads();

    float m = -INFINITY, lsum = 0.0f, o = 0.0f;

    for (int nb = wv; nb * 64 <= last; nb += 4) {
        const int phys = block_tables[b * NBLK + nb];
        const size_t boff = ((size_t)((b * NHEAD + h) * NBLK + phys)) << 12; // *64*64
        const float* __restrict__ Kb = kcache + boff;
        const float* __restrict__ Vb = vcache + boff;

        // scores: lane = slot
        float sc = 0.0f;
        const float4* Krow = (const float4*)(Kb + lane * HD);
        #pragma unroll
        for (int d4 = 0; d4 < 16; ++d4) {
            float4 k4 = Krow[d4];
            float4 q4 = ((const float4*)q_lds)[d4];
            sc = fmaf(k4.x, q4.x, sc);
            sc = fmaf(k4.y, q4.y, sc);
            sc = fmaf(k4.z, q4.z, sc);
            sc = fmaf(k4.w, q4.w, sc);
        }
        const int l = nb * 64 + lane;
        if (l > last) sc = -INFINITY;
        int smax = last - nb * 64; if (smax > 63) smax = 63;  // wave-uniform

        const float bm = wave_max64(sc);
        const float mnew = fmaxf(m, bm);            // finite (block has >=1 valid slot)
        const float alpha = __expf(m - mnew);       // 0 on first block
        const float p = __expf(sc - mnew);          // 0 for masked slots
        lsum = lsum * alpha + wave_sum64(p);
        o *= alpha;
        // PV: lane = d
        for (int s = 0; s <= smax; ++s) {
            const float ps = __shfl(p, s, 64);
            o = fmaf(ps, Vb[s * HD + lane], o);
        }
        m = mnew;
    }

    o_lds[wv][lane] = o;
    if (lane == 0) { ml_lds[wv][0] = m; ml_lds[wv][1] = lsum; }
    __syncthreads();

    if (wv == 0) {
        const float qk = wave_sum64(qd * knd);      // new-token score (finite)
        float Mf = qk;
        #pragma unroll
        for (int w = 0; w < 4; ++w) Mf = fmaxf(Mf, ml_lds[w][0]);
        float osum = 0.0f, Ls = 0.0f;
        #pragma unroll
        for (int w = 0; w < 4; ++w) {
            const float f = __expf(ml_lds[w][0] - Mf);   // 0 for empty waves
            osum = fmaf(o_lds[w][lane], f, osum);
            Ls   = fmaf(ml_lds[w][1], f, Ls);
        }
        const float pn = __expf(qk - Mf);
        osum = fmaf(pn, vnd, osum);
        Ls += pn;
        obuf[base_e + lane] = osum / Ls;
    }
}

extern "C" void kernel_launch(void* const* d_in, const int* in_sizes, int n_in,
                              void* d_out, int out_size, void* d_ws, size_t ws_size,
                              hipStream_t stream) {
    const float* hidden = (const float*)d_in[0];
    const float* kcache = (const float*)d_in[1];
    const float* vcache = (const float*)d_in[2];
    const float* wq = (const float*)d_in[3];
    const float* bq = (const float*)d_in[4];
    const float* wk = (const float*)d_in[5];
    const float* bk = (const float*)d_in[6];
    const float* wvp = (const float*)d_in[7];
    const float* bv = (const float*)d_in[8];
    const float* wo = (const float*)d_in[9];
    const float* bo = (const float*)d_in[10];
    const int* cpos = (const int*)d_in[11];
    const int* btab = (const int*)d_in[12];
    float* out = (float*)d_out;

    float* ws = (float*)d_ws;
    float* qb = ws;                 // 64*1280
    float* kb = ws + 81920;
    float* vb = ws + 163840;
    float* ob = ws + 245760;

    // fused QKV projection: N = 3*1280, BN=16 -> 240 blocks
    proj_gemm<16><<<240, 256, 0, stream>>>(hidden, wq, bq, wk, bk, wvp, bv,
                                           qb, kb, vb, 0.125f);
    // attention: one block per (b,h)
    attn_kernel<<<64 * NHEAD, 256, 0, stream>>>(qb, kb, vb, kcache, vcache,
                                                cpos, btab, ob);
    // output projection: N = 1280, BN=8 -> 160 blocks
    proj_gemm<8><<<160, 256, 0, stream>>>(ob, wo, bo, wo, bo, wo, bo,
                                          out, out, out, 1.0f);
}

// Round 3
// 350.789 us; speedup vs baseline: 1.3762x; 1.3762x over previous
//
#include <hip/hip_runtime.h>
#include <math.h>

#define E 1280
#define NHEAD 20
#define HD 64
#define NBLK 7
#define NB 64

typedef __bf16 bf16x8 __attribute__((ext_vector_type(8)));
typedef __bf16 bf16x4 __attribute__((ext_vector_type(4)));
typedef float floatx4 __attribute__((ext_vector_type(4)));

__device__ __forceinline__ float wave_max64(float v) {
    #pragma unroll
    for (int o = 32; o > 0; o >>= 1) v = fmaxf(v, __shfl_xor(v, o, 64));
    return v;
}
__device__ __forceinline__ float wave_sum64(float v) {
    #pragma unroll
    for (int o = 32; o > 0; o >>= 1) v += __shfl_xor(v, o, 64);
    return v;
}

// C[row][j] = (sum_k A[row][k]*W[j][k] + bias[j]) * scale, bf16 MFMA, fp32 I/O.
// 64 x 16 tile per block, 256 threads (4 waves, wave w owns rows 16w..16w+15).
// grid.x = NTOT/16. QKV: W/bias selected by j/E; q (msel 0) scaled by 0.125.
template<int NTOT, bool QKV>
__global__ __launch_bounds__(256) void mfma_gemm(
    const float* __restrict__ A,
    const float* __restrict__ W0, const float* __restrict__ W1,
    const float* __restrict__ W2,
    const float* __restrict__ b0, const float* __restrict__ b1,
    const float* __restrict__ b2,
    float* __restrict__ C)
{
    __shared__ __align__(16) __bf16 Asl[64][72];   // row stride 144B: 2-way banks (free)
    __shared__ __align__(16) __bf16 Wsl[16][72];

    const int t = threadIdx.x;
    const int lane = t & 63;
    const int wv = t >> 6;
    const int quad = lane >> 4;
    const int l16 = lane & 15;
    const int jg0 = blockIdx.x * 16;

    int j0; const float* Wp; const float* bp; float scl;
    if (QKV) {
        const int msel = jg0 / E;
        j0 = jg0 - msel * E;
        Wp = (msel == 0) ? W0 : ((msel == 1) ? W1 : W2);
        bp = (msel == 0) ? b0 : ((msel == 1) ? b1 : b2);
        scl = (msel == 0) ? 0.125f : 1.0f;
    } else { j0 = jg0; Wp = W0; bp = b0; scl = 1.0f; }

    const int srow = t >> 4;      // staging row group
    const int sc4 = t & 15;       // float4 column within 64-wide K chunk

    floatx4 acc = {0.f, 0.f, 0.f, 0.f};

    for (int k0 = 0; k0 < E; k0 += 64) {
        float4 a4[4];
        #pragma unroll
        for (int r = 0; r < 4; ++r)
            a4[r] = *(const float4*)&A[(size_t)(r * 16 + srow) * E + k0 + sc4 * 4];
        float4 w4 = *(const float4*)&Wp[(size_t)(j0 + srow) * E + k0 + sc4 * 4];

        __syncthreads();
        #pragma unroll
        for (int r = 0; r < 4; ++r) {
            bf16x4 p;
            p[0] = (__bf16)a4[r].x; p[1] = (__bf16)a4[r].y;
            p[2] = (__bf16)a4[r].z; p[3] = (__bf16)a4[r].w;
            *(bf16x4*)&Asl[r * 16 + srow][sc4 * 4] = p;
        }
        {
            bf16x4 p;
            p[0] = (__bf16)w4.x; p[1] = (__bf16)w4.y;
            p[2] = (__bf16)w4.z; p[3] = (__bf16)w4.w;
            *(bf16x4*)&Wsl[srow][sc4 * 4] = p;
        }
        __syncthreads();

        // two K=32 MFMAs per 64-chunk
        bf16x8 af0 = *(const bf16x8*)&Asl[16 * wv + l16][quad * 8];
        bf16x8 bf0 = *(const bf16x8*)&Wsl[l16][quad * 8];
        acc = __builtin_amdgcn_mfma_f32_16x16x32_bf16(af0, bf0, acc, 0, 0, 0);
        bf16x8 af1 = *(const bf16x8*)&Asl[16 * wv + l16][32 + quad * 8];
        bf16x8 bf1 = *(const bf16x8*)&Wsl[l16][32 + quad * 8];
        acc = __builtin_amdgcn_mfma_f32_16x16x32_bf16(af1, bf1, acc, 0, 0, 0);
    }

    // C/D layout: col = lane&15, row = quad*4 + reg  (m89-verified)
    const float bj = bp[j0 + l16];
    #pragma unroll
    for (int r = 0; r < 4; ++r) {
        const int row = 16 * wv + quad * 4 + r;
        C[(size_t)row * NTOT + jg0 + l16] = (acc[r] + bj) * scl;
    }
}

// One block per (b,h). 256 threads = 4 waves. Flash attention, paged KV.
// qkv[64][3840]: q (scaled+biased) | k | v.
__global__ __launch_bounds__(256) void attn_kernel(
    const float* __restrict__ qkv,
    const float* __restrict__ kcache, const float* __restrict__ vcache,
    const int* __restrict__ cache_position, const int* __restrict__ block_tables,
    float* __restrict__ obuf)
{
    const int bh = blockIdx.x;
    const int b = bh / NHEAD;
    const int h = bh % NHEAD;
    const int lane = threadIdx.x & 63;
    const int wv = threadIdx.x >> 6;
    const int d4 = lane & 15;        // float4 group in d
    const int sg = lane >> 4;        // slot subgroup

    __shared__ __align__(16) float q_lds[64];
    __shared__ __align__(16) float o_lds[4][64];
    __shared__ float ml_lds[4][2];

    const int pos = cache_position[b];
    const int last = pos - 1;
    const int col = h * HD + lane;

    const float qd  = qkv[(size_t)b * (3 * E) + col];
    const float knd = qkv[(size_t)b * (3 * E) + E + col];
    const float vnd = qkv[(size_t)b * (3 * E) + 2 * E + col];
    if (wv == 0) q_lds[lane] = qd;
    __syncthreads();

    float m = -INFINITY, lsum = 0.0f;
    float4 vacc = make_float4(0.f, 0.f, 0.f, 0.f);

    for (int nb = wv; nb * 64 <= last; nb += 4) {
        const int phys = block_tables[b * NBLK + nb];
        const size_t boff = ((size_t)((b * NHEAD + h) * NBLK + phys)) << 12; // *64*64
        const float* __restrict__ Kb = kcache + boff;
        const float* __restrict__ Vb = vcache + boff;

        // scores: lane = slot
        float sc = 0.0f;
        const float4* Krow = (const float4*)(Kb + lane * HD);
        #pragma unroll
        for (int dd = 0; dd < 16; ++dd) {
            float4 k4 = Krow[dd];
            float4 q4 = ((const float4*)q_lds)[dd];
            sc = fmaf(k4.x, q4.x, sc);
            sc = fmaf(k4.y, q4.y, sc);
            sc = fmaf(k4.z, q4.z, sc);
            sc = fmaf(k4.w, q4.w, sc);
        }
        const int l = nb * 64 + lane;
        if (l > last) sc = -INFINITY;

        const float bm = wave_max64(sc);
        const float mnew = fmaxf(m, bm);
        const float alpha = __expf(m - mnew);
        const float p = __expf(sc - mnew);
        lsum = lsum * alpha + wave_sum64(p);
        vacc.x *= alpha; vacc.y *= alpha; vacc.z *= alpha; vacc.w *= alpha;

        // PV: lane handles d=[4*d4,4*d4+4), slots s = sg+4j — 16 independent float4 loads
        #pragma unroll
        for (int j = 0; j < 16; ++j) {
            const int s = sg + 4 * j;
            const float ps = __shfl(p, s, 64);
            float4 v4 = *(const float4*)&Vb[s * HD + d4 * 4];
            vacc.x = fmaf(ps, v4.x, vacc.x);
            vacc.y = fmaf(ps, v4.y, vacc.y);
            vacc.z = fmaf(ps, v4.z, vacc.z);
            vacc.w = fmaf(ps, v4.w, vacc.w);
        }
        m = mnew;
    }

    // reduce vacc over the 4 slot subgroups
    #pragma unroll
    for (int o = 16; o <= 32; o <<= 1) {
        vacc.x += __shfl_xor(vacc.x, o, 64);
        vacc.y += __shfl_xor(vacc.y, o, 64);
        vacc.z += __shfl_xor(vacc.z, o, 64);
        vacc.w += __shfl_xor(vacc.w, o, 64);
    }
    if (sg == 0) *(float4*)&o_lds[wv][d4 * 4] = vacc;
    if (lane == 0) { ml_lds[wv][0] = m; ml_lds[wv][1] = lsum; }
    __syncthreads();

    if (wv == 0) {
        const float qk = wave_sum64(qd * knd);   // new-token score (finite)
        float Mf = qk;
        #pragma unroll
        for (int w = 0; w < 4; ++w) Mf = fmaxf(Mf, ml_lds[w][0]);
        float osum = 0.0f, Ls = 0.0f;
        #pragma unroll
        for (int w = 0; w < 4; ++w) {
            const float f = __expf(ml_lds[w][0] - Mf);   // 0 for empty waves
            osum = fmaf(o_lds[w][lane], f, osum);
            Ls   = fmaf(ml_lds[w][1], f, Ls);
        }
        const float pn = __expf(qk - Mf);
        osum = fmaf(pn, vnd, osum);
        Ls += pn;
        obuf[(size_t)b * E + h * HD + lane] = osum / Ls;
    }
}

extern "C" void kernel_launch(void* const* d_in, const int* in_sizes, int n_in,
                              void* d_out, int out_size, void* d_ws, size_t ws_size,
                              hipStream_t stream) {
    const float* hidden = (const float*)d_in[0];
    const float* kcache = (const float*)d_in[1];
    const float* vcache = (const float*)d_in[2];
    const float* wq = (const float*)d_in[3];
    const float* bq = (const float*)d_in[4];
    const float* wk = (const float*)d_in[5];
    const float* bk = (const float*)d_in[6];
    const float* wvp = (const float*)d_in[7];
    const float* bv = (const float*)d_in[8];
    const float* wo = (const float*)d_in[9];
    const float* bo = (const float*)d_in[10];
    const int* cpos = (const int*)d_in[11];
    const int* btab = (const int*)d_in[12];
    float* out = (float*)d_out;

    // ws footprint: 64*3840 + 64*1280 floats = 1.31 MB (= round-1 proven size)
    float* ws = (float*)d_ws;
    float* qkv = ws;                  // 64 x 3840 (q|k|v, bias+scale applied)
    float* ob  = ws + 64 * 3 * E;     // 64 x 1280

    // fused QKV projection: 240 blocks of 64x16
    mfma_gemm<3 * E, true><<<(3 * E) / 16, 256, 0, stream>>>(
        hidden, wq, wk, wvp, bq, bk, bv, qkv);
    // attention: one block per (b,h)
    attn_kernel<<<NB * NHEAD, 256, 0, stream>>>(qkv, kcache, vcache, cpos, btab, ob);
    // output projection: 80 blocks of 64x16, bias fused, direct to d_out
    mfma_gemm<E, false><<<E / 16, 256, 0, stream>>>(
        ob, wo, wo, wo, bo, bo, bo, out);
}

// Round 4
// 338.248 us; speedup vs baseline: 1.4272x; 1.0371x over previous
//
#include <hip/hip_runtime.h>
#include <math.h>

#define E 1280
#define NHEAD 20
#define HD 64
#define NBLK 7
#define NB 64

typedef __bf16 bf16x8 __attribute__((ext_vector_type(8)));
typedef __bf16 bf16x4 __attribute__((ext_vector_type(4)));
typedef float floatx4 __attribute__((ext_vector_type(4)));

__device__ __forceinline__ float wave_max64(float v) {
    #pragma unroll
    for (int o = 32; o > 0; o >>= 1) v = fmaxf(v, __shfl_xor(v, o, 64));
    return v;
}
__device__ __forceinline__ float wave_sum64(float v) {
    #pragma unroll
    for (int o = 32; o > 0; o >>= 1) v += __shfl_xor(v, o, 64);
    return v;
}

__device__ __forceinline__ bf16x4 cvt4(float4 v) {
    bf16x4 p;
    p[0] = (__bf16)v.x; p[1] = (__bf16)v.y; p[2] = (__bf16)v.z; p[3] = (__bf16)v.w;
    return p;
}

// C[row][j] = (sum_k A[row][k]*W[j][k] + bias[j]) * scale, bf16 MFMA, fp32 I/O.
// 64 x 16 tile per block, 256 threads = 4 waves. Wave-split-K: wave w owns
// K range [w*320, w*320+320) with a PRIVATE LDS region -> no barriers in the
// K-loop (sequential depth 5 instead of 20). One barrier + LDS reduction at end.
template<int NTOT, bool QKV>
__global__ __launch_bounds__(256) void mfma_gemm(
    const float* __restrict__ A,
    const float* __restrict__ W0, const float* __restrict__ W1,
    const float* __restrict__ W2,
    const float* __restrict__ b0, const float* __restrict__ b1,
    const float* __restrict__ b2,
    float* __restrict__ C)
{
    __shared__ __align__(16) __bf16 Asl[4][64][72];   // 36 KB, per-wave [wv]
    __shared__ __align__(16) __bf16 Wsl[4][16][72];   // 9 KB, per-wave [wv]

    const int t = threadIdx.x;
    const int lane = t & 63;
    const int wv = t >> 6;
    const int quad = lane >> 4;
    const int l16 = lane & 15;
    const int jg0 = blockIdx.x * 16;

    int j0; const float* Wp; const float* bp; float scl;
    if (QKV) {
        const int msel = jg0 / E;
        j0 = jg0 - msel * E;
        Wp = (msel == 0) ? W0 : ((msel == 1) ? W1 : W2);
        bp = (msel == 0) ? b0 : ((msel == 1) ? b1 : b2);
        scl = (msel == 0) ? 0.125f : 1.0f;
    } else { j0 = jg0; Wp = W0; bp = b0; scl = 1.0f; }

    const int sr = lane >> 2;     // staging row 0..15
    const int sc = lane & 3;      // staging col: float4 index within 16-float run

    floatx4 acc[4] = {};          // 4 row-tiles of 16 rows each

    const int kbeg = wv * (E / 4);           // 320 per wave
    for (int c = 0; c < 5; ++c) {
        const int k0 = kbeg + c * 64;
        // Stage A chunk 64x64: 16 float4/lane. Lanes 0..3 read adjacent float4s
        // (64B runs) -> coalesced. Row = rg*16+sr, col = cg*16 + sc*4.
        #pragma unroll
        for (int rg = 0; rg < 4; ++rg) {
            #pragma unroll
            for (int cg = 0; cg < 4; ++cg) {
                float4 v = *(const float4*)&A[(size_t)(rg * 16 + sr) * E + k0 + cg * 16 + sc * 4];
                *(bf16x4*)&Asl[wv][rg * 16 + sr][cg * 16 + sc * 4] = cvt4(v);
            }
        }
        // Stage W chunk 16x64: 4 float4/lane.
        #pragma unroll
        for (int cg = 0; cg < 4; ++cg) {
            float4 v = *(const float4*)&Wp[(size_t)(j0 + sr) * E + k0 + cg * 16 + sc * 4];
            *(bf16x4*)&Wsl[wv][sr][cg * 16 + sc * 4] = cvt4(v);
        }
        // Wave-private LDS: in-wave ds-write -> ds-read ordering via lgkmcnt only.
        bf16x8 bfr0 = *(const bf16x8*)&Wsl[wv][l16][quad * 8];
        bf16x8 bfr1 = *(const bf16x8*)&Wsl[wv][l16][32 + quad * 8];
        #pragma unroll
        for (int rg = 0; rg < 4; ++rg) {
            bf16x8 af0 = *(const bf16x8*)&Asl[wv][rg * 16 + l16][quad * 8];
            acc[rg] = __builtin_amdgcn_mfma_f32_16x16x32_bf16(af0, bfr0, acc[rg], 0, 0, 0);
            bf16x8 af1 = *(const bf16x8*)&Asl[wv][rg * 16 + l16][32 + quad * 8];
            acc[rg] = __builtin_amdgcn_mfma_f32_16x16x32_bf16(af1, bfr1, acc[rg], 0, 0, 0);
        }
    }

    // Cross-wave reduction: alias first 16 KB of Asl as float [4][64][16].
    __syncthreads();
    float (*Cred)[64][16] = (float (*)[64][16])&Asl[0][0][0];
    // C/D layout: col = lane&15, row = quad*4 + reg (m89-verified)
    #pragma unroll
    for (int r = 0; r < 4; ++r) {
        #pragma unroll
        for (int rg = 0; rg < 4; ++rg)
            ;  // (layout note: write below)
        ;
    }
    #pragma unroll
    for (int rg = 0; rg < 4; ++rg) {
        #pragma unroll
        for (int r = 0; r < 4; ++r)
            Cred[wv][rg * 16 + quad * 4 + r][l16] = acc[rg][r];
    }
    __syncthreads();

    // 1024 outputs, 4 per thread; consecutive t -> consecutive elements (coalesced).
    #pragma unroll
    for (int i = 0; i < 4; ++i) {
        const int e = t + i * 256;
        const int row = e >> 4, col = e & 15;
        float s = Cred[0][row][col] + Cred[1][row][col]
                + Cred[2][row][col] + Cred[3][row][col];
        C[(size_t)row * NTOT + jg0 + col] = (s + bp[j0 + col]) * scl;
    }
}

// One block per (b,h). 256 threads = 4 waves. Flash attention, paged KV.
// qkv[64][3840]: q (scaled+biased) | k | v.
__global__ __launch_bounds__(256) void attn_kernel(
    const float* __restrict__ qkv,
    const float* __restrict__ kcache, const float* __restrict__ vcache,
    const int* __restrict__ cache_position, const int* __restrict__ block_tables,
    float* __restrict__ obuf)
{
    const int bh = blockIdx.x;
    const int b = bh / NHEAD;
    const int h = bh % NHEAD;
    const int lane = threadIdx.x & 63;
    const int wv = threadIdx.x >> 6;
    const int d4 = lane & 15;        // float4 group in d
    const int sg = lane >> 4;        // slot subgroup

    __shared__ __align__(16) float q_lds[64];
    __shared__ __align__(16) float o_lds[4][64];
    __shared__ float ml_lds[4][2];

    const int pos = cache_position[b];
    const int last = pos - 1;
    const int col = h * HD + lane;

    const float qd  = qkv[(size_t)b * (3 * E) + col];
    const float knd = qkv[(size_t)b * (3 * E) + E + col];
    const float vnd = qkv[(size_t)b * (3 * E) + 2 * E + col];
    if (wv == 0) q_lds[lane] = qd;
    __syncthreads();

    float m = -INFINITY, lsum = 0.0f;
    float4 vacc = make_float4(0.f, 0.f, 0.f, 0.f);

    for (int nb = wv; nb * 64 <= last; nb += 4) {
        const int phys = block_tables[b * NBLK + nb];
        const size_t boff = ((size_t)((b * NHEAD + h) * NBLK + phys)) << 12; // *64*64
        const float* __restrict__ Kb = kcache + boff;
        const float* __restrict__ Vb = vcache + boff;

        // scores: lane = slot
        float sc = 0.0f;
        const float4* Krow = (const float4*)(Kb + lane * HD);
        #pragma unroll
        for (int dd = 0; dd < 16; ++dd) {
            float4 k4 = Krow[dd];
            float4 q4 = ((const float4*)q_lds)[dd];
            sc = fmaf(k4.x, q4.x, sc);
            sc = fmaf(k4.y, q4.y, sc);
            sc = fmaf(k4.z, q4.z, sc);
            sc = fmaf(k4.w, q4.w, sc);
        }
        const int l = nb * 64 + lane;
        if (l > last) sc = -INFINITY;

        const float bm = wave_max64(sc);
        const float mnew = fmaxf(m, bm);
        const float alpha = __expf(m - mnew);
        const float p = __expf(sc - mnew);
        lsum = lsum * alpha + wave_sum64(p);
        vacc.x *= alpha; vacc.y *= alpha; vacc.z *= alpha; vacc.w *= alpha;

        // PV: lane handles d=[4*d4,4*d4+4), slots s = sg+4j — 16 independent float4 loads
        #pragma unroll
        for (int j = 0; j < 16; ++j) {
            const int s = sg + 4 * j;
            const float ps = __shfl(p, s, 64);
            float4 v4 = *(const float4*)&Vb[s * HD + d4 * 4];
            vacc.x = fmaf(ps, v4.x, vacc.x);
            vacc.y = fmaf(ps, v4.y, vacc.y);
            vacc.z = fmaf(ps, v4.z, vacc.z);
            vacc.w = fmaf(ps, v4.w, vacc.w);
        }
        m = mnew;
    }

    // reduce vacc over the 4 slot subgroups
    #pragma unroll
    for (int o = 16; o <= 32; o <<= 1) {
        vacc.x += __shfl_xor(vacc.x, o, 64);
        vacc.y += __shfl_xor(vacc.y, o, 64);
        vacc.z += __shfl_xor(vacc.z, o, 64);
        vacc.w += __shfl_xor(vacc.w, o, 64);
    }
    if (sg == 0) *(float4*)&o_lds[wv][d4 * 4] = vacc;
    if (lane == 0) { ml_lds[wv][0] = m; ml_lds[wv][1] = lsum; }
    __syncthreads();

    if (wv == 0) {
        const float qk = wave_sum64(qd * knd);   // new-token score (finite)
        float Mf = qk;
        #pragma unroll
        for (int w = 0; w < 4; ++w) Mf = fmaxf(Mf, ml_lds[w][0]);
        float osum = 0.0f, Ls = 0.0f;
        #pragma unroll
        for (int w = 0; w < 4; ++w) {
            const float f = __expf(ml_lds[w][0] - Mf);   // 0 for empty waves
            osum = fmaf(o_lds[w][lane], f, osum);
            Ls   = fmaf(ml_lds[w][1], f, Ls);
        }
        const float pn = __expf(qk - Mf);
        osum = fmaf(pn, vnd, osum);
        Ls += pn;
        obuf[(size_t)b * E + h * HD + lane] = osum / Ls;
    }
}

extern "C" void kernel_launch(void* const* d_in, const int* in_sizes, int n_in,
                              void* d_out, int out_size, void* d_ws, size_t ws_size,
                              hipStream_t stream) {
    const float* hidden = (const float*)d_in[0];
    const float* kcache = (const float*)d_in[1];
    const float* vcache = (const float*)d_in[2];
    const float* wq = (const float*)d_in[3];
    const float* bq = (const float*)d_in[4];
    const float* wk = (const float*)d_in[5];
    const float* bk = (const float*)d_in[6];
    const float* wvp = (const float*)d_in[7];
    const float* bv = (const float*)d_in[8];
    const float* wo = (const float*)d_in[9];
    const float* bo = (const float*)d_in[10];
    const int* cpos = (const int*)d_in[11];
    const int* btab = (const int*)d_in[12];
    float* out = (float*)d_out;

    // ws footprint: 64*3840 + 64*1280 floats = 1.31 MB (proven safe)
    float* ws = (float*)d_ws;
    float* qkv = ws;                  // 64 x 3840 (q|k|v, bias+scale applied)
    float* ob  = ws + 64 * 3 * E;     // 64 x 1280

    // fused QKV projection: 240 blocks of 64x16
    mfma_gemm<3 * E, true><<<(3 * E) / 16, 256, 0, stream>>>(
        hidden, wq, wk, wvp, bq, bk, bv, qkv);
    // attention: one block per (b,h)
    attn_kernel<<<NB * NHEAD, 256, 0, stream>>>(qkv, kcache, vcache, cpos, btab, ob);
    // output projection: 80 blocks of 64x16, bias fused, direct to d_out
    mfma_gemm<E, false><<<E / 16, 256, 0, stream>>>(
        ob, wo, wo, wo, bo, bo, bo, out);
}